// Round 9
// baseline (653.241 us; speedup 1.0000x reference)
//
#include <hip/hip_runtime.h>
#include <hip/hip_bf16.h>

#define HDIM 512
#define TILE 32
#define TPB 512

typedef __attribute__((ext_vector_type(8))) short short8;
typedef __attribute__((ext_vector_type(4))) short s16x4;
typedef __attribute__((ext_vector_type(4))) float f32x4;

__device__ __forceinline__ unsigned short f2bf(float x) {
  __hip_bfloat16 h = __float2bfloat16(x);
  return *reinterpret_cast<unsigned short*>(&h);
}
__device__ __forceinline__ float bf2f(unsigned short h) {
  return __uint_as_float(((unsigned)h) << 16);
}
// sigmoid via v_rcp_f32 (1-ulp) instead of IEEE divide.
__device__ __forceinline__ float fsig(float z) {
  return __builtin_amdgcn_rcpf(1.f + __expf(-z));
}
// bufA is [e][n] (TILE x 512 bf16). XOR bits 4-6 of n with e&7: b64 C-stores
// land 2-way (free); b128 B-frag reads conflict-free.
__device__ __forceinline__ int bidx(int e, int n) {
  return e * HDIM + (n ^ ((e & 7) << 4));
}

// W2 (512x512 f32 [k][n]) -> bf16 MFMA A-fragment-major, fwd B[k][n], bwd B[n][k].
__global__ void prep_weights(const float* __restrict__ pW2, const float* __restrict__ tW2,
                             unsigned short* __restrict__ pWf, unsigned short* __restrict__ pWb,
                             unsigned short* __restrict__ tWf, unsigned short* __restrict__ tWb) {
  int i = blockIdx.x * blockDim.x + threadIdx.x;
  if (i >= HDIM * HDIM) return;
  int j  = i & 7;
  int l  = (i >> 3) & 63;
  int kb = (i >> 9) & 15;
  int nb = i >> 13;
  int kpos = kb * 32 + ((l >> 4) << 3) + j;
  int npos = nb * 16 + (l & 15);
  pWf[i] = f2bf(pW2[kpos * HDIM + npos]);
  pWb[i] = f2bf(pW2[npos * HDIM + kpos]);
  tWf[i] = f2bf(tW2[kpos * HDIM + npos]);
  tWb[i] = f2bf(tW2[npos * HDIM + kpos]);
}

// W1 ([IN][512] f32) -> layer-1 A-fragments (hi/lo split-bf16, K=32 zero-padded)
// and phase-5 A-fragments (A[g][n] = W1[g][n], g < GD).
__global__ void prep_w1(const float* __restrict__ W1, int IN, int GD,
                        unsigned short* __restrict__ hi, unsigned short* __restrict__ lo,
                        unsigned short* __restrict__ p5) {
  int i = blockIdx.x * blockDim.x + threadIdx.x;
  if (i < 32 * 64 * 8) {               // layer-1 frags: [nb=32][lane][j]
    int j = i & 7, l = (i >> 3) & 63, nb = i >> 9;
    int k = ((l >> 4) << 3) + j;
    int col = nb * 16 + (l & 15);
    float v = (k < IN) ? W1[k * HDIM + col] : 0.f;
    unsigned short h = f2bf(v);
    hi[i] = h;
    lo[i] = f2bf(v - bf2f(h));
  } else if (i < 32 * 64 * 8 + 16 * 64 * 8) {  // phase-5 frags: [kk=16][lane][j]
    int i2 = i - 32 * 64 * 8;
    int j = i2 & 7, l = (i2 >> 3) & 63, kk = i2 >> 9;
    int lm = l & 15, q = l >> 4;
    int k = kk * 32 + q * 8 + j;
    p5[i2] = f2bf((lm < GD) ? W1[lm * HDIM + k] : 0.f);
  }
}

// One merged kernel: blocks [0,nb2) handle pair edges, [nb2, nb2+nb3) triples.
// Phases 1-4 are arity-independent (prep zero-pads); arity is block-uniform.
__global__ void __launch_bounds__(TPB, 2)   // VGPR clamp 128 (empirical 256/w)
energy_kernel(const float* __restrict__ x, const float* __restrict__ sigp,
              const int* __restrict__ ep, const int* __restrict__ et,
              int E2, int E3, int nb2,
              const unsigned short* __restrict__ pW1hi, const unsigned short* __restrict__ pW1lo,
              const unsigned short* __restrict__ pW1p5,
              const unsigned short* __restrict__ tW1hi, const unsigned short* __restrict__ tW1lo,
              const unsigned short* __restrict__ tW1p5,
              const float* __restrict__ pb1, const float* __restrict__ tb1,
              const unsigned short* __restrict__ pWf, const unsigned short* __restrict__ pWb,
              const unsigned short* __restrict__ tWf, const unsigned short* __restrict__ tWb,
              const float* __restrict__ pb2, const float* __restrict__ tb2,
              const float* __restrict__ pw3, const float* __restrict__ tw3,
              const float* __restrict__ pb3, const float* __restrict__ tb3,
              float* __restrict__ out) {
  __shared__ __align__(16) unsigned short bufA[TILE * HDIM];  // h1 -> dz2 -> dz1 (32 KB)
  __shared__ __align__(16) float h0s[TILE][16];
  __shared__ float dh0sT[8][TILE];
  __shared__ int   idxs[TILE * 3];
  __shared__ float blockE;

  const bool isP = (int)blockIdx.x < nb2;
  const int arity = isP ? 2 : 3;
  const int GD = 2 * arity;
  const int Etot = isP ? E2 : E3;
  const int* __restrict__ edges = isP ? ep : et;
  const unsigned short* __restrict__ W1hi = isP ? pW1hi : tW1hi;
  const unsigned short* __restrict__ W1lo = isP ? pW1lo : tW1lo;
  const unsigned short* __restrict__ W1p5 = isP ? pW1p5 : tW1p5;
  const unsigned short* __restrict__ Wf = isP ? pWf : tWf;
  const unsigned short* __restrict__ Wb = isP ? pWb : tWb;
  const float* __restrict__ b1 = isP ? pb1 : tb1;
  const float* __restrict__ b2 = isP ? pb2 : tb2;
  const float* __restrict__ w3 = isP ? pw3 : tw3;
  const float* __restrict__ b3p = isP ? pb3 : tb3;

  const int tid  = threadIdx.x;
  const int lane = tid & 63;
  const int w    = tid >> 6;            // 8 waves; wave owns n-cols [w*64, w*64+64)
  const int q    = lane >> 4;
  const int lm   = lane & 15;
  const int tile0 = (isP ? (int)blockIdx.x : (int)blockIdx.x - nb2) * TILE;
  const int vcnt  = min(TILE, Etot - tile0);
  const float sigma = sigp[0];

  // ---- phase 0: init ----
  if (tid == 0) blockE = 0.f;
  if (tid < 256) ((float*)dh0sT)[tid] = 0.f;
  if (tid < TILE * arity) {
    int e = tid / arity;
    idxs[tid] = (e < vcnt) ? edges[(size_t)tile0 * arity + tid] : 0;
  }
  __syncthreads();
  if (tid < TILE) {
#pragma unroll
    for (int k = 0; k < 16; ++k) h0s[tid][k] = 0.f;
    if (tid < vcnt) {
      for (int o = 0; o < arity; ++o) {
        int id = idxs[tid * arity + o];
        h0s[tid][o * 2 + 0] = x[id * 2 + 0];
        h0s[tid][o * 2 + 1] = x[id * 2 + 1];
        h0s[tid][arity * 2 + o] = sigma;
      }
    }
  }
  __syncthreads();

  const int n0 = w * 64;

  // ---- h0 B-fragments (hi/lo split), lane gives h0[ef*16+lm][q*8+j] ----
  short8 Hh[2], Hl[2];
#pragma unroll
  for (int ef = 0; ef < 2; ++ef) {
    f32x4 v0 = {0.f, 0.f, 0.f, 0.f}, v1 = {0.f, 0.f, 0.f, 0.f};
    if (q < 2) {
      const float* p = &h0s[ef * 16 + lm][q * 8];
      v0 = *(const f32x4*)p;
      v1 = *(const f32x4*)(p + 4);
    }
#pragma unroll
    for (int j = 0; j < 4; ++j) {
      unsigned short ha = f2bf(v0[j]);
      Hh[ef][j] = (short)ha;
      Hl[ef][j] = (short)f2bf(v0[j] - bf2f(ha));
      unsigned short hb = f2bf(v1[j]);
      Hh[ef][j + 4] = (short)hb;
      Hl[ef][j + 4] = (short)f2bf(v1[j] - bf2f(hb));
    }
  }

  f32x4 acc[4][2];
#pragma unroll
  for (int mf = 0; mf < 4; ++mf)
#pragma unroll
    for (int ef = 0; ef < 2; ++ef) acc[mf][ef] = (f32x4){0.f, 0.f, 0.f, 0.f};

  // ---- phase 1: z1^T = W1^T h0^T via split-bf16 MFMA ----
#pragma unroll
  for (int mf = 0; mf < 4; ++mf) {
    short8 A1h = *(const short8*)(W1hi + (((w * 4 + mf) * 64 + lane) << 3));
    short8 A1l = *(const short8*)(W1lo + (((w * 4 + mf) * 64 + lane) << 3));
#pragma unroll
    for (int ef = 0; ef < 2; ++ef) {
      acc[mf][ef] = __builtin_amdgcn_mfma_f32_16x16x32_bf16(A1h, Hh[ef], acc[mf][ef], 0, 0, 0);
      acc[mf][ef] = __builtin_amdgcn_mfma_f32_16x16x32_bf16(A1l, Hh[ef], acc[mf][ef], 0, 0, 0);
      acc[mf][ef] = __builtin_amdgcn_mfma_f32_16x16x32_bf16(A1h, Hl[ef], acc[mf][ef], 0, 0, 0);
    }
  }
  // silu(z1) -> bufA[e][n], one b64 per fragment
#pragma unroll
  for (int mf = 0; mf < 4; ++mf) {
    f32x4 b1x = *(const f32x4*)&b1[n0 + mf * 16 + q * 4];
#pragma unroll
    for (int ef = 0; ef < 2; ++ef) {
      bool val = (ef * 16 + lm) < vcnt;
      s16x4 pk;
#pragma unroll
      for (int r = 0; r < 4; ++r) {
        float z = acc[mf][ef][r] + b1x[r];
        float s = fsig(z);
        pk[r] = (short)f2bf(val ? z * s : 0.f);
      }
      *(s16x4*)&bufA[bidx(ef * 16 + lm, n0 + mf * 16 + q * 4)] = pk;
    }
  }
  __syncthreads();

  // ---- phase 2: z2^T = W2^T h1^T ----
#pragma unroll
  for (int mf = 0; mf < 4; ++mf)
#pragma unroll
    for (int ef = 0; ef < 2; ++ef) acc[mf][ef] = (f32x4){0.f, 0.f, 0.f, 0.f};

#pragma unroll 4
  for (int kk = 0; kk < 16; ++kk) {
    short8 hb[2];
#pragma unroll
    for (int ef = 0; ef < 2; ++ef)
      hb[ef] = *(const short8*)&bufA[bidx(ef * 16 + lm, kk * 32 + q * 8)];
#pragma unroll
    for (int mf = 0; mf < 4; ++mf) {
      short8 af = *(const short8*)(Wf + ((((w * 4 + mf) * 16 + kk) * 64 + lane) << 3));
#pragma unroll
      for (int ef = 0; ef < 2; ++ef)
        acc[mf][ef] = __builtin_amdgcn_mfma_f32_16x16x32_bf16(af, hb[ef], acc[mf][ef], 0, 0, 0);
    }
  }

  // ---- epilogue fwd: energy + dz2 = w3*silu'(z2) ----
  float epart = 0.f;
#pragma unroll
  for (int mf = 0; mf < 4; ++mf) {
    f32x4 b2x = *(const f32x4*)&b2[n0 + mf * 16 + q * 4];
    f32x4 w3x = *(const f32x4*)&w3[n0 + mf * 16 + q * 4];
#pragma unroll
    for (int ef = 0; ef < 2; ++ef) {
      bool val = (ef * 16 + lm) < vcnt;
#pragma unroll
      for (int r = 0; r < 4; ++r) {
        float z = acc[mf][ef][r] + b2x[r];
        float s = fsig(z);
        float h2 = z * s;
        float sp = s * (1.f + z * (1.f - s));
        epart += val ? h2 * w3x[r] : 0.f;
        acc[mf][ef][r] = val ? w3x[r] * sp : 0.f;
      }
    }
  }
#pragma unroll
  for (int off = 32; off > 0; off >>= 1) epart += __shfl_down(epart, off, 64);
  if (lane == 0) atomicAdd(&blockE, epart);

  __syncthreads();  // all reads of h1 done
#pragma unroll
  for (int mf = 0; mf < 4; ++mf)
#pragma unroll
    for (int ef = 0; ef < 2; ++ef) {
      s16x4 pk;
#pragma unroll
      for (int r = 0; r < 4; ++r) pk[r] = (short)f2bf(acc[mf][ef][r]);
      *(s16x4*)&bufA[bidx(ef * 16 + lm, n0 + mf * 16 + q * 4)] = pk;
    }
  __syncthreads();
  if (tid == 0) atomicAdd(out, blockE + (float)vcnt * b3p[0]);

  // ---- phase 3: dH1^T = W2 dz2^T ----
#pragma unroll
  for (int mf = 0; mf < 4; ++mf)
#pragma unroll
    for (int ef = 0; ef < 2; ++ef) acc[mf][ef] = (f32x4){0.f, 0.f, 0.f, 0.f};

#pragma unroll 4
  for (int kk = 0; kk < 16; ++kk) {
    short8 hb[2];
#pragma unroll
    for (int ef = 0; ef < 2; ++ef)
      hb[ef] = *(const short8*)&bufA[bidx(ef * 16 + lm, kk * 32 + q * 8)];
#pragma unroll
    for (int mf = 0; mf < 4; ++mf) {
      short8 af = *(const short8*)(Wb + ((((w * 4 + mf) * 16 + kk) * 64 + lane) << 3));
#pragma unroll
      for (int ef = 0; ef < 2; ++ef)
        acc[mf][ef] = __builtin_amdgcn_mfma_f32_16x16x32_bf16(af, hb[ef], acc[mf][ef], 0, 0, 0);
    }
  }

  // ---- phase 4: dz1 = dH1 * silu'(z1); z1 via bf16 re-MFMA ----
#pragma unroll
  for (int mf = 0; mf < 4; ++mf) {
    short8 A1h = *(const short8*)(W1hi + (((w * 4 + mf) * 64 + lane) << 3));
    f32x4 zacc[2];
#pragma unroll
    for (int ef = 0; ef < 2; ++ef) zacc[ef] = (f32x4){0.f, 0.f, 0.f, 0.f};
#pragma unroll
    for (int ef = 0; ef < 2; ++ef)
      zacc[ef] = __builtin_amdgcn_mfma_f32_16x16x32_bf16(A1h, Hh[ef], zacc[ef], 0, 0, 0);
    f32x4 b1x = *(const f32x4*)&b1[n0 + mf * 16 + q * 4];
#pragma unroll
    for (int ef = 0; ef < 2; ++ef)
#pragma unroll
      for (int r = 0; r < 4; ++r) {
        float z = zacc[ef][r] + b1x[r];
        float s = fsig(z);
        float sp = s * (1.f + z * (1.f - s));
        acc[mf][ef][r] *= sp;
      }
  }
  __syncthreads();  // all reads of dz2 done
#pragma unroll
  for (int mf = 0; mf < 4; ++mf)
#pragma unroll
    for (int ef = 0; ef < 2; ++ef) {
      s16x4 pk;
#pragma unroll
      for (int r = 0; r < 4; ++r) pk[r] = (short)f2bf(acc[mf][ef][r]);
      *(s16x4*)&bufA[bidx(ef * 16 + lm, n0 + mf * 16 + q * 4)] = pk;
    }
  __syncthreads();

  // ---- phase 5: dh0^T = W1 dz1^T, K(n) split across 8 waves ----
  {
    f32x4 pacc[2];
#pragma unroll
    for (int ef = 0; ef < 2; ++ef) pacc[ef] = (f32x4){0.f, 0.f, 0.f, 0.f};
#pragma unroll
    for (int t = 0; t < 2; ++t) {
      int kk = w * 2 + t;
      short8 a5 = *(const short8*)(W1p5 + ((kk * 64 + lane) << 3));
      short8 db[2];
#pragma unroll
      for (int ef = 0; ef < 2; ++ef)
        db[ef] = *(const short8*)&bufA[bidx(ef * 16 + lm, kk * 32 + q * 8)];
#pragma unroll
      for (int ef = 0; ef < 2; ++ef)
        pacc[ef] = __builtin_amdgcn_mfma_f32_16x16x32_bf16(a5, db[ef], pacc[ef], 0, 0, 0);
    }
#pragma unroll
    for (int ef = 0; ef < 2; ++ef)
#pragma unroll
      for (int r = 0; r < 4; ++r) {
        int g = q * 4 + r;
        if (g < GD) atomicAdd(&dh0sT[g][ef * 16 + lm], pacc[ef][r]);
      }
  }
  __syncthreads();

  // ---- scatter grads ----
  if (tid < 256) {
    int e = tid & 31, g = tid >> 5;     // 32 edges x 8 comps
    if (e < vcnt && g < GD) {
      int obj = g >> 1, d = g & 1;
      atomicAdd(&out[1 + idxs[e * arity + obj] * 2 + d], dh0sT[g][e]);
    }
  }
}

extern "C" void kernel_launch(void* const* d_in, const int* in_sizes, int n_in,
                              void* d_out, int out_size, void* d_ws, size_t ws_size,
                              hipStream_t stream) {
  const float* x    = (const float*)d_in[0];
  const float* sig  = (const float*)d_in[1];
  const int*   ep   = (const int*)d_in[2];
  const int*   et   = (const int*)d_in[3];
  const float* pW1  = (const float*)d_in[4];
  const float* pb1  = (const float*)d_in[5];
  const float* pW2  = (const float*)d_in[6];
  const float* pb2  = (const float*)d_in[7];
  const float* pW3  = (const float*)d_in[8];
  const float* pb3  = (const float*)d_in[9];
  const float* tW1  = (const float*)d_in[10];
  const float* tb1  = (const float*)d_in[11];
  const float* tW2  = (const float*)d_in[12];
  const float* tb2  = (const float*)d_in[13];
  const float* tW3  = (const float*)d_in[14];
  const float* tb3  = (const float*)d_in[15];
  const int E2 = in_sizes[2] / 2;
  const int E3 = in_sizes[3] / 3;
  float* out = (float*)d_out;

  unsigned short* pWf = (unsigned short*)d_ws;
  unsigned short* pWb = pWf + HDIM * HDIM;
  unsigned short* tWf = pWb + HDIM * HDIM;
  unsigned short* tWb = tWf + HDIM * HDIM;
  unsigned short* pW1hi = tWb + HDIM * HDIM;
  unsigned short* pW1lo = pW1hi + 32 * 64 * 8;
  unsigned short* pW1p5 = pW1lo + 32 * 64 * 8;
  unsigned short* tW1hi = pW1p5 + 16 * 64 * 8;
  unsigned short* tW1lo = tW1hi + 32 * 64 * 8;
  unsigned short* tW1p5 = tW1lo + 32 * 64 * 8;

  const int nb2 = (E2 + TILE - 1) / TILE;
  const int nb3 = (E3 + TILE - 1) / TILE;

  hipMemsetAsync(d_out, 0, (size_t)out_size * sizeof(float), stream);
  prep_weights<<<(HDIM * HDIM + 255) / 256, 256, 0, stream>>>(pW2, tW2, pWf, pWb, tWf, tWb);
  prep_w1<<<(32 * 64 * 8 + 16 * 64 * 8 + 255) / 256, 256, 0, stream>>>(pW1, 6, 4, pW1hi, pW1lo, pW1p5);
  prep_w1<<<(32 * 64 * 8 + 16 * 64 * 8 + 255) / 256, 256, 0, stream>>>(tW1, 9, 6, tW1hi, tW1lo, tW1p5);
  energy_kernel<<<nb2 + nb3, TPB, 0, stream>>>(
      x, sig, ep, et, E2, E3, nb2,
      pW1hi, pW1lo, pW1p5, tW1hi, tW1lo, tW1p5, pb1, tb1,
      pWf, pWb, tWf, tWb, pb2, tb2, pW3, tW3, pb3, tb3, out);
}

// Round 10
// 458.720 us; speedup vs baseline: 1.4241x; 1.4241x over previous
//
#include <hip/hip_runtime.h>
#include <hip/hip_bf16.h>

#define HDIM 512
#define TILE 64
#define TPB 512

typedef __attribute__((ext_vector_type(8))) short short8;
typedef __attribute__((ext_vector_type(4))) short s16x4;
typedef __attribute__((ext_vector_type(4))) float f32x4;

__device__ __forceinline__ unsigned short f2bf(float x) {
  __hip_bfloat16 h = __float2bfloat16(x);
  return *reinterpret_cast<unsigned short*>(&h);
}
__device__ __forceinline__ float bf2f(unsigned short h) {
  return __uint_as_float(((unsigned)h) << 16);
}
// sigmoid via v_rcp_f32 (1-ulp) instead of IEEE divide.
__device__ __forceinline__ float fsig(float z) {
  return __builtin_amdgcn_rcpf(1.f + __expf(-z));
}
// bufA is [e][n] (TILE x 512 bf16). XOR bits 4-6 of n with e&7: b64 C-stores
// land 2-way (free); b128 B-frag reads conflict-free.
__device__ __forceinline__ int bidx(int e, int n) {
  return e * HDIM + (n ^ ((e & 7) << 4));
}

// W2 (512x512 f32 [k][n]) -> bf16 MFMA A-fragment-major, fwd B[k][n], bwd B[n][k].
__global__ void prep_weights(const float* __restrict__ pW2, const float* __restrict__ tW2,
                             unsigned short* __restrict__ pWf, unsigned short* __restrict__ pWb,
                             unsigned short* __restrict__ tWf, unsigned short* __restrict__ tWb) {
  int i = blockIdx.x * blockDim.x + threadIdx.x;
  if (i >= HDIM * HDIM) return;
  int j  = i & 7;
  int l  = (i >> 3) & 63;
  int kb = (i >> 9) & 15;
  int nb = i >> 13;
  int kpos = kb * 32 + ((l >> 4) << 3) + j;
  int npos = nb * 16 + (l & 15);
  pWf[i] = f2bf(pW2[kpos * HDIM + npos]);
  pWb[i] = f2bf(pW2[npos * HDIM + kpos]);
  tWf[i] = f2bf(tW2[kpos * HDIM + npos]);
  tWb[i] = f2bf(tW2[npos * HDIM + kpos]);
}

// W1 ([IN][512] f32) -> layer-1 A-fragments (hi/lo split-bf16, K=32 zero-padded)
// and phase-5 A-fragments (A[g][n] = W1[g][n], g < GD).
__global__ void prep_w1(const float* __restrict__ W1, int IN, int GD,
                        unsigned short* __restrict__ hi, unsigned short* __restrict__ lo,
                        unsigned short* __restrict__ p5) {
  int i = blockIdx.x * blockDim.x + threadIdx.x;
  if (i < 32 * 64 * 8) {               // layer-1 frags: [nb=32][lane][j]
    int j = i & 7, l = (i >> 3) & 63, nb = i >> 9;
    int k = ((l >> 4) << 3) + j;
    int col = nb * 16 + (l & 15);
    float v = (k < IN) ? W1[k * HDIM + col] : 0.f;
    unsigned short h = f2bf(v);
    hi[i] = h;
    lo[i] = f2bf(v - bf2f(h));
  } else if (i < 32 * 64 * 8 + 16 * 64 * 8) {  // phase-5 frags: [kk=16][lane][j]
    int i2 = i - 32 * 64 * 8;
    int j = i2 & 7, l = (i2 >> 3) & 63, kk = i2 >> 9;
    int lm = l & 15, q = l >> 4;
    int k = kk * 32 + q * 8 + j;
    p5[i2] = f2bf((lm < GD) ? W1[lm * HDIM + k] : 0.f);
  }
}

// One merged kernel: blocks [0,nb2) handle pair edges, [nb2, nb2+nb3) triples.
__global__ void __launch_bounds__(TPB, 2)   // VGPR clamp 128 (empirical 256/w)
energy_kernel(const float* __restrict__ x, const float* __restrict__ sigp,
              const int* __restrict__ ep, const int* __restrict__ et,
              int E2, int E3, int nb2,
              const unsigned short* __restrict__ pW1hi, const unsigned short* __restrict__ pW1lo,
              const unsigned short* __restrict__ pW1p5,
              const unsigned short* __restrict__ tW1hi, const unsigned short* __restrict__ tW1lo,
              const unsigned short* __restrict__ tW1p5,
              const float* __restrict__ pb1, const float* __restrict__ tb1,
              const unsigned short* __restrict__ pWf, const unsigned short* __restrict__ pWb,
              const unsigned short* __restrict__ tWf, const unsigned short* __restrict__ tWb,
              const float* __restrict__ pb2, const float* __restrict__ tb2,
              const float* __restrict__ pw3, const float* __restrict__ tw3,
              const float* __restrict__ pb3, const float* __restrict__ tb3,
              float* __restrict__ out) {
  __shared__ __align__(16) unsigned short bufA[TILE * HDIM];  // h1 -> dz2 -> dz1 (64 KB)
  __shared__ __align__(16) float h0s[TILE][16];
  __shared__ float dh0sT[8][TILE];
  __shared__ int   idxs[TILE * 3];
  __shared__ float blockE;

  const bool isP = (int)blockIdx.x < nb2;
  const int arity = isP ? 2 : 3;
  const int GD = 2 * arity;
  const int Etot = isP ? E2 : E3;
  const int* __restrict__ edges = isP ? ep : et;
  const unsigned short* __restrict__ W1hi = isP ? pW1hi : tW1hi;
  const unsigned short* __restrict__ W1lo = isP ? pW1lo : tW1lo;
  const unsigned short* __restrict__ W1p5 = isP ? pW1p5 : tW1p5;
  const unsigned short* __restrict__ Wf = isP ? pWf : tWf;
  const unsigned short* __restrict__ Wb = isP ? pWb : tWb;
  const float* __restrict__ b1 = isP ? pb1 : tb1;
  const float* __restrict__ b2 = isP ? pb2 : tb2;
  const float* __restrict__ w3 = isP ? pw3 : tw3;
  const float* __restrict__ b3p = isP ? pb3 : tb3;

  const int tid  = threadIdx.x;
  const int lane = tid & 63;
  const int w    = tid >> 6;            // 8 waves; wave owns n-cols [w*64, w*64+64)
  const int q    = lane >> 4;
  const int lm   = lane & 15;
  const int tile0 = (isP ? (int)blockIdx.x : (int)blockIdx.x - nb2) * TILE;
  const int vcnt  = min(TILE, Etot - tile0);
  const float sigma = sigp[0];

  // ---- phase 0: init ----
  if (tid == 0) blockE = 0.f;
  ((float*)dh0sT)[tid] = 0.f;           // 8*64 == 512 == TPB
  if (tid < TILE * arity) {
    int e = tid / arity;
    idxs[tid] = (e < vcnt) ? edges[(size_t)tile0 * arity + tid] : 0;
  }
  __syncthreads();
  if (tid < TILE) {
#pragma unroll
    for (int k = 0; k < 16; ++k) h0s[tid][k] = 0.f;
    if (tid < vcnt) {
      for (int o = 0; o < arity; ++o) {
        int id = idxs[tid * arity + o];
        h0s[tid][o * 2 + 0] = x[id * 2 + 0];
        h0s[tid][o * 2 + 1] = x[id * 2 + 1];
        h0s[tid][arity * 2 + o] = sigma;
      }
    }
  }
  __syncthreads();

  const int n0 = w * 64;

  // ---- h0 B-fragments (hi/lo split), lane gives h0[ef*16+lm][q*8+j] ----
  short8 Hh[4], Hl[4];
#pragma unroll
  for (int ef = 0; ef < 4; ++ef) {
    f32x4 v0 = {0.f, 0.f, 0.f, 0.f}, v1 = {0.f, 0.f, 0.f, 0.f};
    if (q < 2) {
      const float* p = &h0s[ef * 16 + lm][q * 8];
      v0 = *(const f32x4*)p;
      v1 = *(const f32x4*)(p + 4);
    }
#pragma unroll
    for (int j = 0; j < 4; ++j) {
      unsigned short ha = f2bf(v0[j]);
      Hh[ef][j] = (short)ha;
      Hl[ef][j] = (short)f2bf(v0[j] - bf2f(ha));
      unsigned short hb = f2bf(v1[j]);
      Hh[ef][j + 4] = (short)hb;
      Hl[ef][j + 4] = (short)f2bf(v1[j] - bf2f(hb));
    }
  }

  f32x4 acc[4][4];
#pragma unroll
  for (int mf = 0; mf < 4; ++mf)
#pragma unroll
    for (int ef = 0; ef < 4; ++ef) acc[mf][ef] = (f32x4){0.f, 0.f, 0.f, 0.f};

  // ---- phase 1: z1^T = W1^T h0^T via split-bf16 MFMA ----
#pragma unroll
  for (int mf = 0; mf < 4; ++mf) {
    short8 A1h = *(const short8*)(W1hi + (((w * 4 + mf) * 64 + lane) << 3));
    short8 A1l = *(const short8*)(W1lo + (((w * 4 + mf) * 64 + lane) << 3));
#pragma unroll
    for (int ef = 0; ef < 4; ++ef) {
      acc[mf][ef] = __builtin_amdgcn_mfma_f32_16x16x32_bf16(A1h, Hh[ef], acc[mf][ef], 0, 0, 0);
      acc[mf][ef] = __builtin_amdgcn_mfma_f32_16x16x32_bf16(A1l, Hh[ef], acc[mf][ef], 0, 0, 0);
      acc[mf][ef] = __builtin_amdgcn_mfma_f32_16x16x32_bf16(A1h, Hl[ef], acc[mf][ef], 0, 0, 0);
    }
  }
  // silu(z1) -> bufA[e][n], one b64 per fragment
#pragma unroll
  for (int mf = 0; mf < 4; ++mf) {
    f32x4 b1x = *(const f32x4*)&b1[n0 + mf * 16 + q * 4];
#pragma unroll
    for (int ef = 0; ef < 4; ++ef) {
      bool val = (ef * 16 + lm) < vcnt;
      s16x4 pk;
#pragma unroll
      for (int r = 0; r < 4; ++r) {
        float z = acc[mf][ef][r] + b1x[r];
        float s = fsig(z);
        pk[r] = (short)f2bf(val ? z * s : 0.f);
      }
      *(s16x4*)&bufA[bidx(ef * 16 + lm, n0 + mf * 16 + q * 4)] = pk;
    }
  }
  __syncthreads();

  // ---- phase 2: z2^T = W2^T h1^T ----
#pragma unroll
  for (int mf = 0; mf < 4; ++mf)
#pragma unroll
    for (int ef = 0; ef < 4; ++ef) acc[mf][ef] = (f32x4){0.f, 0.f, 0.f, 0.f};

#pragma unroll 2
  for (int kk = 0; kk < 16; ++kk) {
    short8 hb[4];
#pragma unroll
    for (int ef = 0; ef < 4; ++ef)
      hb[ef] = *(const short8*)&bufA[bidx(ef * 16 + lm, kk * 32 + q * 8)];
#pragma unroll
    for (int mf = 0; mf < 4; ++mf) {
      short8 af = *(const short8*)(Wf + ((((w * 4 + mf) * 16 + kk) * 64 + lane) << 3));
#pragma unroll
      for (int ef = 0; ef < 4; ++ef)
        acc[mf][ef] = __builtin_amdgcn_mfma_f32_16x16x32_bf16(af, hb[ef], acc[mf][ef], 0, 0, 0);
    }
  }

  // ---- epilogue fwd: energy + dz2 = w3*silu'(z2) ----
  float epart = 0.f;
#pragma unroll
  for (int mf = 0; mf < 4; ++mf) {
    f32x4 b2x = *(const f32x4*)&b2[n0 + mf * 16 + q * 4];
    f32x4 w3x = *(const f32x4*)&w3[n0 + mf * 16 + q * 4];
#pragma unroll
    for (int ef = 0; ef < 4; ++ef) {
      bool val = (ef * 16 + lm) < vcnt;
#pragma unroll
      for (int r = 0; r < 4; ++r) {
        float z = acc[mf][ef][r] + b2x[r];
        float s = fsig(z);
        float h2 = z * s;
        float sp = s * (1.f + z * (1.f - s));
        epart += val ? h2 * w3x[r] : 0.f;
        acc[mf][ef][r] = val ? w3x[r] * sp : 0.f;
      }
    }
  }
#pragma unroll
  for (int off = 32; off > 0; off >>= 1) epart += __shfl_down(epart, off, 64);
  if (lane == 0) atomicAdd(&blockE, epart);

  __syncthreads();  // all reads of h1 done
#pragma unroll
  for (int mf = 0; mf < 4; ++mf)
#pragma unroll
    for (int ef = 0; ef < 4; ++ef) {
      s16x4 pk;
#pragma unroll
      for (int r = 0; r < 4; ++r) pk[r] = (short)f2bf(acc[mf][ef][r]);
      *(s16x4*)&bufA[bidx(ef * 16 + lm, n0 + mf * 16 + q * 4)] = pk;
    }
  __syncthreads();
  if (tid == 0) atomicAdd(out, blockE + (float)vcnt * b3p[0]);

  // ---- phase 3: dH1^T = W2 dz2^T ----
#pragma unroll
  for (int mf = 0; mf < 4; ++mf)
#pragma unroll
    for (int ef = 0; ef < 4; ++ef) acc[mf][ef] = (f32x4){0.f, 0.f, 0.f, 0.f};

#pragma unroll 2
  for (int kk = 0; kk < 16; ++kk) {
    short8 hb[4];
#pragma unroll
    for (int ef = 0; ef < 4; ++ef)
      hb[ef] = *(const short8*)&bufA[bidx(ef * 16 + lm, kk * 32 + q * 8)];
#pragma unroll
    for (int mf = 0; mf < 4; ++mf) {
      short8 af = *(const short8*)(Wb + ((((w * 4 + mf) * 16 + kk) * 64 + lane) << 3));
#pragma unroll
      for (int ef = 0; ef < 4; ++ef)
        acc[mf][ef] = __builtin_amdgcn_mfma_f32_16x16x32_bf16(af, hb[ef], acc[mf][ef], 0, 0, 0);
    }
  }

  // ---- phase 4: dz1 = dH1 * silu'(z1); z1 via bf16 re-MFMA ----
#pragma unroll
  for (int mf = 0; mf < 4; ++mf) {
    short8 A1h = *(const short8*)(W1hi + (((w * 4 + mf) * 64 + lane) << 3));
    f32x4 zacc[4];
#pragma unroll
    for (int ef = 0; ef < 4; ++ef) zacc[ef] = (f32x4){0.f, 0.f, 0.f, 0.f};
#pragma unroll
    for (int ef = 0; ef < 4; ++ef)
      zacc[ef] = __builtin_amdgcn_mfma_f32_16x16x32_bf16(A1h, Hh[ef], zacc[ef], 0, 0, 0);
    f32x4 b1x = *(const f32x4*)&b1[n0 + mf * 16 + q * 4];
#pragma unroll
    for (int ef = 0; ef < 4; ++ef)
#pragma unroll
      for (int r = 0; r < 4; ++r) {
        float z = zacc[ef][r] + b1x[r];
        float s = fsig(z);
        float sp = s * (1.f + z * (1.f - s));
        acc[mf][ef][r] *= sp;
      }
  }
  __syncthreads();  // all reads of dz2 done
#pragma unroll
  for (int mf = 0; mf < 4; ++mf)
#pragma unroll
    for (int ef = 0; ef < 4; ++ef) {
      s16x4 pk;
#pragma unroll
      for (int r = 0; r < 4; ++r) pk[r] = (short)f2bf(acc[mf][ef][r]);
      *(s16x4*)&bufA[bidx(ef * 16 + lm, n0 + mf * 16 + q * 4)] = pk;
    }
  __syncthreads();

  // ---- phase 5: dh0^T = W1 dz1^T, K(n) split across 8 waves ----
  {
    f32x4 pacc[4];
#pragma unroll
    for (int ef = 0; ef < 4; ++ef) pacc[ef] = (f32x4){0.f, 0.f, 0.f, 0.f};
#pragma unroll
    for (int t = 0; t < 2; ++t) {
      int kk = w * 2 + t;
      short8 a5 = *(const short8*)(W1p5 + ((kk * 64 + lane) << 3));
      short8 db[4];
#pragma unroll
      for (int ef = 0; ef < 4; ++ef)
        db[ef] = *(const short8*)&bufA[bidx(ef * 16 + lm, kk * 32 + q * 8)];
#pragma unroll
      for (int ef = 0; ef < 4; ++ef)
        pacc[ef] = __builtin_amdgcn_mfma_f32_16x16x32_bf16(a5, db[ef], pacc[ef], 0, 0, 0);
    }
#pragma unroll
    for (int ef = 0; ef < 4; ++ef)
#pragma unroll
      for (int r = 0; r < 4; ++r) {
        int g = q * 4 + r;
        if (g < GD) atomicAdd(&dh0sT[g][ef * 16 + lm], pacc[ef][r]);
      }
  }
  __syncthreads();

  // ---- scatter grads ----
  {
    int e = tid & 63, g = tid >> 6;     // 512 threads = 64 edges x 8 comps
    if (e < vcnt && g < GD) {
      int obj = g >> 1, d = g & 1;
      atomicAdd(&out[1 + idxs[e * arity + obj] * 2 + d], dh0sT[g][e]);
    }
  }
}

extern "C" void kernel_launch(void* const* d_in, const int* in_sizes, int n_in,
                              void* d_out, int out_size, void* d_ws, size_t ws_size,
                              hipStream_t stream) {
  const float* x    = (const float*)d_in[0];
  const float* sig  = (const float*)d_in[1];
  const int*   ep   = (const int*)d_in[2];
  const int*   et   = (const int*)d_in[3];
  const float* pW1  = (const float*)d_in[4];
  const float* pb1  = (const float*)d_in[5];
  const float* pW2  = (const float*)d_in[6];
  const float* pb2  = (const float*)d_in[7];
  const float* pW3  = (const float*)d_in[8];
  const float* pb3  = (const float*)d_in[9];
  const float* tW1  = (const float*)d_in[10];
  const float* tb1  = (const float*)d_in[11];
  const float* tW2  = (const float*)d_in[12];
  const float* tb2  = (const float*)d_in[13];
  const float* tW3  = (const float*)d_in[14];
  const float* tb3  = (const float*)d_in[15];
  const int E2 = in_sizes[2] / 2;
  const int E3 = in_sizes[3] / 3;
  float* out = (float*)d_out;

  unsigned short* pWf = (unsigned short*)d_ws;
  unsigned short* pWb = pWf + HDIM * HDIM;
  unsigned short* tWf = pWb + HDIM * HDIM;
  unsigned short* tWb = tWf + HDIM * HDIM;
  unsigned short* pW1hi = tWb + HDIM * HDIM;
  unsigned short* pW1lo = pW1hi + 32 * 64 * 8;
  unsigned short* pW1p5 = pW1lo + 32 * 64 * 8;
  unsigned short* tW1hi = pW1p5 + 16 * 64 * 8;
  unsigned short* tW1lo = tW1hi + 32 * 64 * 8;
  unsigned short* tW1p5 = tW1lo + 32 * 64 * 8;

  const int nb2 = (E2 + TILE - 1) / TILE;
  const int nb3 = (E3 + TILE - 1) / TILE;

  hipMemsetAsync(d_out, 0, (size_t)out_size * sizeof(float), stream);
  prep_weights<<<(HDIM * HDIM + 255) / 256, 256, 0, stream>>>(pW2, tW2, pWf, pWb, tWf, tWb);
  prep_w1<<<(32 * 64 * 8 + 16 * 64 * 8 + 255) / 256, 256, 0, stream>>>(pW1, 6, 4, pW1hi, pW1lo, pW1p5);
  prep_w1<<<(32 * 64 * 8 + 16 * 64 * 8 + 255) / 256, 256, 0, stream>>>(tW1, 9, 6, tW1hi, tW1lo, tW1p5);
  energy_kernel<<<nb2 + nb3, TPB, 0, stream>>>(
      x, sig, ep, et, E2, E3, nb2,
      pW1hi, pW1lo, pW1p5, tW1hi, tW1lo, tW1p5, pb1, tb1,
      pWf, pWb, tWf, tWb, pb2, tb2, pW3, tW3, pb3, tb3, out);
}

// Round 11
// 436.776 us; speedup vs baseline: 1.4956x; 1.0502x over previous
//
#include <hip/hip_runtime.h>
#include <hip/hip_bf16.h>

#define HDIM 512
#define TILE 64
#define TPB 512

typedef __attribute__((ext_vector_type(8))) short short8;
typedef __attribute__((ext_vector_type(4))) short s16x4;
typedef __attribute__((ext_vector_type(4))) float f32x4;

__device__ __forceinline__ unsigned short f2bf(float x) {
  __hip_bfloat16 h = __float2bfloat16(x);
  return *reinterpret_cast<unsigned short*>(&h);
}
__device__ __forceinline__ float bf2f(unsigned short h) {
  return __uint_as_float(((unsigned)h) << 16);
}
// sigmoid via v_rcp_f32 (1-ulp) instead of IEEE divide.
__device__ __forceinline__ float fsig(float z) {
  return __builtin_amdgcn_rcpf(1.f + __expf(-z));
}
// bufA is [e][n] (TILE x 512 bf16). XOR bits 4-6 of n with e&7: b64 C-stores
// land 2-way (free); b128 B-frag reads 2-way (free).
__device__ __forceinline__ int bidx(int e, int n) {
  return e * HDIM + (n ^ ((e & 7) << 4));
}

// W2 (512x512 f32 [k][n]) -> bf16 MFMA A-fragment-major, fwd B[k][n], bwd B[n][k].
__global__ void prep_weights(const float* __restrict__ pW2, const float* __restrict__ tW2,
                             unsigned short* __restrict__ pWf, unsigned short* __restrict__ pWb,
                             unsigned short* __restrict__ tWf, unsigned short* __restrict__ tWb) {
  int i = blockIdx.x * blockDim.x + threadIdx.x;
  if (i >= HDIM * HDIM) return;
  int j  = i & 7;
  int l  = (i >> 3) & 63;
  int kb = (i >> 9) & 15;
  int nb = i >> 13;
  int kpos = kb * 32 + ((l >> 4) << 3) + j;
  int npos = nb * 16 + (l & 15);
  pWf[i] = f2bf(pW2[kpos * HDIM + npos]);
  pWb[i] = f2bf(pW2[npos * HDIM + kpos]);
  tWf[i] = f2bf(tW2[kpos * HDIM + npos]);
  tWb[i] = f2bf(tW2[npos * HDIM + kpos]);
}

// W1 ([IN][512] f32) -> layer-1 A-fragments (hi/lo split-bf16, K=32 zero-padded)
// and phase-5 A-fragments (A[g][n] = W1[g][n], g < GD).
__global__ void prep_w1(const float* __restrict__ W1, int IN, int GD,
                        unsigned short* __restrict__ hi, unsigned short* __restrict__ lo,
                        unsigned short* __restrict__ p5) {
  int i = blockIdx.x * blockDim.x + threadIdx.x;
  if (i < 32 * 64 * 8) {               // layer-1 frags: [nb=32][lane][j]
    int j = i & 7, l = (i >> 3) & 63, nb = i >> 9;
    int k = ((l >> 4) << 3) + j;
    int col = nb * 16 + (l & 15);
    float v = (k < IN) ? W1[k * HDIM + col] : 0.f;
    unsigned short h = f2bf(v);
    hi[i] = h;
    lo[i] = f2bf(v - bf2f(h));
  } else if (i < 32 * 64 * 8 + 16 * 64 * 8) {  // phase-5 frags: [kk=16][lane][j]
    int i2 = i - 32 * 64 * 8;
    int j = i2 & 7, l = (i2 >> 3) & 63, kk = i2 >> 9;
    int lm = l & 15, q = l >> 4;
    int k = kk * 32 + q * 8 + j;
    p5[i2] = f2bf((lm < GD) ? W1[lm * HDIM + k] : 0.f);
  }
}

// One merged kernel: blocks [0,nb2) handle pair edges, [nb2, nb2+nb3) triples.
__global__ void __launch_bounds__(TPB, 2)   // VGPR clamp 128 (empirical 256/w)
energy_kernel(const float* __restrict__ x, const float* __restrict__ sigp,
              const int* __restrict__ ep, const int* __restrict__ et,
              int E2, int E3, int nb2,
              const unsigned short* __restrict__ pW1hi, const unsigned short* __restrict__ pW1lo,
              const unsigned short* __restrict__ pW1p5,
              const unsigned short* __restrict__ tW1hi, const unsigned short* __restrict__ tW1lo,
              const unsigned short* __restrict__ tW1p5,
              const float* __restrict__ pb1, const float* __restrict__ tb1,
              const unsigned short* __restrict__ pWf, const unsigned short* __restrict__ pWb,
              const unsigned short* __restrict__ tWf, const unsigned short* __restrict__ tWb,
              const float* __restrict__ pb2, const float* __restrict__ tb2,
              const float* __restrict__ pw3, const float* __restrict__ tw3,
              const float* __restrict__ pb3, const float* __restrict__ tb3,
              float* __restrict__ out) {
  __shared__ __align__(16) unsigned short bufA[TILE * HDIM];  // h1 -> dz2 -> dz1 (64 KB)
  __shared__ __align__(16) float h0s[TILE][16];
  __shared__ float dh0sT[8][TILE];
  __shared__ int   idxs[TILE * 3];
  __shared__ float blockE;

  const bool isP = (int)blockIdx.x < nb2;
  const int arity = isP ? 2 : 3;
  const int GD = 2 * arity;
  const int Etot = isP ? E2 : E3;
  const int* __restrict__ edges = isP ? ep : et;
  const unsigned short* __restrict__ W1hi = isP ? pW1hi : tW1hi;
  const unsigned short* __restrict__ W1lo = isP ? pW1lo : tW1lo;
  const unsigned short* __restrict__ W1p5 = isP ? pW1p5 : tW1p5;
  const unsigned short* __restrict__ Wf = isP ? pWf : tWf;
  const unsigned short* __restrict__ Wb = isP ? pWb : tWb;
  const float* __restrict__ b1 = isP ? pb1 : tb1;
  const float* __restrict__ b2 = isP ? pb2 : tb2;
  const float* __restrict__ w3 = isP ? pw3 : tw3;
  const float* __restrict__ b3p = isP ? pb3 : tb3;

  const int tid  = threadIdx.x;
  const int lane = tid & 63;
  const int w    = tid >> 6;            // 8 waves; wave owns n-cols [w*64, w*64+64)
  const int q    = lane >> 4;
  const int lm   = lane & 15;
  const int tile0 = (isP ? (int)blockIdx.x : (int)blockIdx.x - nb2) * TILE;
  const int vcnt  = min(TILE, Etot - tile0);
  const float sigma = sigp[0];

  // ---- phase 0: init ----
  if (tid == 0) blockE = 0.f;
  ((float*)dh0sT)[tid] = 0.f;           // 8*64 == 512 == TPB
  if (tid < TILE * arity) {
    int e = tid / arity;
    idxs[tid] = (e < vcnt) ? edges[(size_t)tile0 * arity + tid] : 0;
  }
  __syncthreads();
  if (tid < TILE) {
#pragma unroll
    for (int k = 0; k < 16; ++k) h0s[tid][k] = 0.f;
    if (tid < vcnt) {
      for (int o = 0; o < arity; ++o) {
        int id = idxs[tid * arity + o];
        h0s[tid][o * 2 + 0] = x[id * 2 + 0];
        h0s[tid][o * 2 + 1] = x[id * 2 + 1];
        h0s[tid][arity * 2 + o] = sigma;
      }
    }
  }
  __syncthreads();

  const int n0 = w * 64;

  // ---- h0 B-fragments (hi/lo split), lane gives h0[ef*16+lm][q*8+j] ----
  short8 Hh[4], Hl[4];
#pragma unroll
  for (int ef = 0; ef < 4; ++ef) {
    f32x4 v0 = {0.f, 0.f, 0.f, 0.f}, v1 = {0.f, 0.f, 0.f, 0.f};
    if (q < 2) {
      const float* p = &h0s[ef * 16 + lm][q * 8];
      v0 = *(const f32x4*)p;
      v1 = *(const f32x4*)(p + 4);
    }
#pragma unroll
    for (int j = 0; j < 4; ++j) {
      unsigned short ha = f2bf(v0[j]);
      Hh[ef][j] = (short)ha;
      Hl[ef][j] = (short)f2bf(v0[j] - bf2f(ha));
      unsigned short hb = f2bf(v1[j]);
      Hh[ef][j + 4] = (short)hb;
      Hl[ef][j + 4] = (short)f2bf(v1[j] - bf2f(hb));
    }
  }

  f32x4 acc[4][4];
#pragma unroll
  for (int mf = 0; mf < 4; ++mf)
#pragma unroll
    for (int ef = 0; ef < 4; ++ef) acc[mf][ef] = (f32x4){0.f, 0.f, 0.f, 0.f};

  // ---- phase 1: z1^T = W1^T h0^T via split-bf16 MFMA ----
#pragma unroll
  for (int mf = 0; mf < 4; ++mf) {
    short8 A1h = *(const short8*)(W1hi + (((w * 4 + mf) * 64 + lane) << 3));
    short8 A1l = *(const short8*)(W1lo + (((w * 4 + mf) * 64 + lane) << 3));
#pragma unroll
    for (int ef = 0; ef < 4; ++ef) {
      acc[mf][ef] = __builtin_amdgcn_mfma_f32_16x16x32_bf16(A1h, Hh[ef], acc[mf][ef], 0, 0, 0);
      acc[mf][ef] = __builtin_amdgcn_mfma_f32_16x16x32_bf16(A1l, Hh[ef], acc[mf][ef], 0, 0, 0);
      acc[mf][ef] = __builtin_amdgcn_mfma_f32_16x16x32_bf16(A1h, Hl[ef], acc[mf][ef], 0, 0, 0);
    }
  }
  // silu(z1) -> bufA[e][n], one b64 per fragment
#pragma unroll
  for (int mf = 0; mf < 4; ++mf) {
    f32x4 b1x = *(const f32x4*)&b1[n0 + mf * 16 + q * 4];
#pragma unroll
    for (int ef = 0; ef < 4; ++ef) {
      bool val = (ef * 16 + lm) < vcnt;
      s16x4 pk;
#pragma unroll
      for (int r = 0; r < 4; ++r) {
        float z = acc[mf][ef][r] + b1x[r];
        float s = fsig(z);
        pk[r] = (short)f2bf(val ? z * s : 0.f);
      }
      *(s16x4*)&bufA[bidx(ef * 16 + lm, n0 + mf * 16 + q * 4)] = pk;
    }
  }
  __syncthreads();

  // ---- phase 2: z2^T = W2^T h1^T, depth-1 af prefetch + setprio ----
#pragma unroll
  for (int mf = 0; mf < 4; ++mf)
#pragma unroll
    for (int ef = 0; ef < 4; ++ef) acc[mf][ef] = (f32x4){0.f, 0.f, 0.f, 0.f};

  {
    short8 af_cur[4];
#pragma unroll
    for (int mf = 0; mf < 4; ++mf)
      af_cur[mf] = *(const short8*)(Wf + ((((w * 4 + mf) * 16 + 0) * 64 + lane) << 3));
#pragma unroll
    for (int kk = 0; kk < 16; ++kk) {
      short8 af_nxt[4];
      if (kk < 15) {
#pragma unroll
        for (int mf = 0; mf < 4; ++mf)
          af_nxt[mf] = *(const short8*)(Wf + ((((w * 4 + mf) * 16 + kk + 1) * 64 + lane) << 3));
      }
      short8 hb[4];
#pragma unroll
      for (int ef = 0; ef < 4; ++ef)
        hb[ef] = *(const short8*)&bufA[bidx(ef * 16 + lm, kk * 32 + q * 8)];
      __builtin_amdgcn_s_setprio(1);
#pragma unroll
      for (int mf = 0; mf < 4; ++mf)
#pragma unroll
        for (int ef = 0; ef < 4; ++ef)
          acc[mf][ef] = __builtin_amdgcn_mfma_f32_16x16x32_bf16(af_cur[mf], hb[ef], acc[mf][ef], 0, 0, 0);
      __builtin_amdgcn_s_setprio(0);
#pragma unroll
      for (int mf = 0; mf < 4; ++mf) af_cur[mf] = af_nxt[mf];
    }
  }

  // ---- epilogue fwd: energy + dz2 = w3*silu'(z2) ----
  float epart = 0.f;
#pragma unroll
  for (int mf = 0; mf < 4; ++mf) {
    f32x4 b2x = *(const f32x4*)&b2[n0 + mf * 16 + q * 4];
    f32x4 w3x = *(const f32x4*)&w3[n0 + mf * 16 + q * 4];
#pragma unroll
    for (int ef = 0; ef < 4; ++ef) {
      bool val = (ef * 16 + lm) < vcnt;
#pragma unroll
      for (int r = 0; r < 4; ++r) {
        float z = acc[mf][ef][r] + b2x[r];
        float s = fsig(z);
        float h2 = z * s;
        float sp = s * (1.f + z * (1.f - s));
        epart += val ? h2 * w3x[r] : 0.f;
        acc[mf][ef][r] = val ? w3x[r] * sp : 0.f;
      }
    }
  }
#pragma unroll
  for (int off = 32; off > 0; off >>= 1) epart += __shfl_down(epart, off, 64);
  if (lane == 0) atomicAdd(&blockE, epart);

  __syncthreads();  // all reads of h1 done
#pragma unroll
  for (int mf = 0; mf < 4; ++mf)
#pragma unroll
    for (int ef = 0; ef < 4; ++ef) {
      s16x4 pk;
#pragma unroll
      for (int r = 0; r < 4; ++r) pk[r] = (short)f2bf(acc[mf][ef][r]);
      *(s16x4*)&bufA[bidx(ef * 16 + lm, n0 + mf * 16 + q * 4)] = pk;
    }
  __syncthreads();
  if (tid == 0) atomicAdd(out, blockE + (float)vcnt * b3p[0]);

  // ---- phase 3: dH1^T = W2 dz2^T, depth-1 af prefetch + setprio ----
#pragma unroll
  for (int mf = 0; mf < 4; ++mf)
#pragma unroll
    for (int ef = 0; ef < 4; ++ef) acc[mf][ef] = (f32x4){0.f, 0.f, 0.f, 0.f};

  {
    short8 af_cur[4];
#pragma unroll
    for (int mf = 0; mf < 4; ++mf)
      af_cur[mf] = *(const short8*)(Wb + ((((w * 4 + mf) * 16 + 0) * 64 + lane) << 3));
#pragma unroll
    for (int kk = 0; kk < 16; ++kk) {
      short8 af_nxt[4];
      if (kk < 15) {
#pragma unroll
        for (int mf = 0; mf < 4; ++mf)
          af_nxt[mf] = *(const short8*)(Wb + ((((w * 4 + mf) * 16 + kk + 1) * 64 + lane) << 3));
      }
      short8 hb[4];
#pragma unroll
      for (int ef = 0; ef < 4; ++ef)
        hb[ef] = *(const short8*)&bufA[bidx(ef * 16 + lm, kk * 32 + q * 8)];
      __builtin_amdgcn_s_setprio(1);
#pragma unroll
      for (int mf = 0; mf < 4; ++mf)
#pragma unroll
        for (int ef = 0; ef < 4; ++ef)
          acc[mf][ef] = __builtin_amdgcn_mfma_f32_16x16x32_bf16(af_cur[mf], hb[ef], acc[mf][ef], 0, 0, 0);
      __builtin_amdgcn_s_setprio(0);
#pragma unroll
      for (int mf = 0; mf < 4; ++mf) af_cur[mf] = af_nxt[mf];
    }
  }

  // ---- phase 4: dz1 = dH1 * silu'(z1); z1 via bf16 re-MFMA ----
#pragma unroll
  for (int mf = 0; mf < 4; ++mf) {
    short8 A1h = *(const short8*)(W1hi + (((w * 4 + mf) * 64 + lane) << 3));
    f32x4 zacc[4];
#pragma unroll
    for (int ef = 0; ef < 4; ++ef) zacc[ef] = (f32x4){0.f, 0.f, 0.f, 0.f};
#pragma unroll
    for (int ef = 0; ef < 4; ++ef)
      zacc[ef] = __builtin_amdgcn_mfma_f32_16x16x32_bf16(A1h, Hh[ef], zacc[ef], 0, 0, 0);
    f32x4 b1x = *(const f32x4*)&b1[n0 + mf * 16 + q * 4];
#pragma unroll
    for (int ef = 0; ef < 4; ++ef)
#pragma unroll
      for (int r = 0; r < 4; ++r) {
        float z = zacc[ef][r] + b1x[r];
        float s = fsig(z);
        float sp = s * (1.f + z * (1.f - s));
        acc[mf][ef][r] *= sp;
      }
  }
  __syncthreads();  // all reads of dz2 done
#pragma unroll
  for (int mf = 0; mf < 4; ++mf)
#pragma unroll
    for (int ef = 0; ef < 4; ++ef) {
      s16x4 pk;
#pragma unroll
      for (int r = 0; r < 4; ++r) pk[r] = (short)f2bf(acc[mf][ef][r]);
      *(s16x4*)&bufA[bidx(ef * 16 + lm, n0 + mf * 16 + q * 4)] = pk;
    }
  __syncthreads();

  // ---- phase 5: dh0^T = W1 dz1^T, K(n) split across 8 waves ----
  {
    f32x4 pacc[4];
#pragma unroll
    for (int ef = 0; ef < 4; ++ef) pacc[ef] = (f32x4){0.f, 0.f, 0.f, 0.f};
#pragma unroll
    for (int t = 0; t < 2; ++t) {
      int kk = w * 2 + t;
      short8 a5 = *(const short8*)(W1p5 + ((kk * 64 + lane) << 3));
      short8 db[4];
#pragma unroll
      for (int ef = 0; ef < 4; ++ef)
        db[ef] = *(const short8*)&bufA[bidx(ef * 16 + lm, kk * 32 + q * 8)];
#pragma unroll
      for (int ef = 0; ef < 4; ++ef)
        pacc[ef] = __builtin_amdgcn_mfma_f32_16x16x32_bf16(a5, db[ef], pacc[ef], 0, 0, 0);
    }
#pragma unroll
    for (int ef = 0; ef < 4; ++ef)
#pragma unroll
      for (int r = 0; r < 4; ++r) {
        int g = q * 4 + r;
        if (g < GD) atomicAdd(&dh0sT[g][ef * 16 + lm], pacc[ef][r]);
      }
  }
  __syncthreads();

  // ---- scatter grads ----
  {
    int e = tid & 63, g = tid >> 6;     // 512 threads = 64 edges x 8 comps
    if (e < vcnt && g < GD) {
      int obj = g >> 1, d = g & 1;
      atomicAdd(&out[1 + idxs[e * arity + obj] * 2 + d], dh0sT[g][e]);
    }
  }
}

extern "C" void kernel_launch(void* const* d_in, const int* in_sizes, int n_in,
                              void* d_out, int out_size, void* d_ws, size_t ws_size,
                              hipStream_t stream) {
  const float* x    = (const float*)d_in[0];
  const float* sig  = (const float*)d_in[1];
  const int*   ep   = (const int*)d_in[2];
  const int*   et   = (const int*)d_in[3];
  const float* pW1  = (const float*)d_in[4];
  const float* pb1  = (const float*)d_in[5];
  const float* pW2  = (const float*)d_in[6];
  const float* pb2  = (const float*)d_in[7];
  const float* pW3  = (const float*)d_in[8];
  const float* pb3  = (const float*)d_in[9];
  const float* tW1  = (const float*)d_in[10];
  const float* tb1  = (const float*)d_in[11];
  const float* tW2  = (const float*)d_in[12];
  const float* tb2  = (const float*)d_in[13];
  const float* tW3  = (const float*)d_in[14];
  const float* tb3  = (const float*)d_in[15];
  const int E2 = in_sizes[2] / 2;
  const int E3 = in_sizes[3] / 3;
  float* out = (float*)d_out;

  unsigned short* pWf = (unsigned short*)d_ws;
  unsigned short* pWb = pWf + HDIM * HDIM;
  unsigned short* tWf = pWb + HDIM * HDIM;
  unsigned short* tWb = tWf + HDIM * HDIM;
  unsigned short* pW1hi = tWb + HDIM * HDIM;
  unsigned short* pW1lo = pW1hi + 32 * 64 * 8;
  unsigned short* pW1p5 = pW1lo + 32 * 64 * 8;
  unsigned short* tW1hi = pW1p5 + 16 * 64 * 8;
  unsigned short* tW1lo = tW1hi + 32 * 64 * 8;
  unsigned short* tW1p5 = tW1lo + 32 * 64 * 8;

  const int nb2 = (E2 + TILE - 1) / TILE;
  const int nb3 = (E3 + TILE - 1) / TILE;

  hipMemsetAsync(d_out, 0, (size_t)out_size * sizeof(float), stream);
  prep_weights<<<(HDIM * HDIM + 255) / 256, 256, 0, stream>>>(pW2, tW2, pWf, pWb, tWf, tWb);
  prep_w1<<<(32 * 64 * 8 + 16 * 64 * 8 + 255) / 256, 256, 0, stream>>>(pW1, 6, 4, pW1hi, pW1lo, pW1p5);
  prep_w1<<<(32 * 64 * 8 + 16 * 64 * 8 + 255) / 256, 256, 0, stream>>>(tW1, 9, 6, tW1hi, tW1lo, tW1p5);
  energy_kernel<<<nb2 + nb3, TPB, 0, stream>>>(
      x, sig, ep, et, E2, E3, nb2,
      pW1hi, pW1lo, pW1p5, tW1hi, tW1lo, tW1p5, pb1, tb1,
      pWf, pWb, tWf, tWb, pb2, tb2, pW3, tW3, pb3, tb3, out);
}